// Round 1
// baseline (31.055 us; speedup 1.0000x reference)
//
#include <hip/hip_runtime.h>

// DiffNet collapsed-conv fused layers.
// Layer math (exact reformulation of the reference):
//   Wv = vi @ W.T                    [B, O]   (pre-bias)
//   vj = relu(Wv + bias)             [B, O]
//   A_c = sum_h c2w[h] * c1w[h][c]   (c = 0:input, 1:weight, 2:output)
//   D   = sum_h c2w[h] * c1b[h] + c2b
//   s1[b] = sum_i vi[b][i];  s2[b] = sum_i vi[b][i]^2
//   delta[b][o] = scale * (A0*s2[b] + A1*Wv[b][o] + (A2*vj[b][o] + D)*s1[b])
//   out = vj + delta
// scale = 0.1 / batch_num.

template<int IIN, int ROWS>
__launch_bounds__(256, 2)
__global__ void diffnet_layer(const float* __restrict__ vi,   // [32, IIN]
                              const float* __restrict__ W,    // [Oout, IIN]
                              const float* __restrict__ bias, // [Oout]
                              const float* __restrict__ c1w,  // [8,3]
                              const float* __restrict__ c1b,  // [8]
                              const float* __restrict__ c2w,  // [8]
                              const float* __restrict__ c2b,  // [1]
                              const int* __restrict__ bn,     // [1]
                              float* __restrict__ outp,       // [32, Oout]
                              int Oout)
{
    __shared__ float vis[ROWS * IIN];
    __shared__ float s1s[ROWS];
    __shared__ float s2s[ROWS];

    const int tid   = threadIdx.x;
    const int lane  = tid & 63;
    const int wave  = tid >> 6;
    const int brow0 = blockIdx.y * ROWS;

    // ---- stage vi rows into LDS (coalesced float4) ----
    {
        const float4* src = reinterpret_cast<const float4*>(vi + brow0 * IIN);
        float4* dst = reinterpret_cast<float4*>(vis);
        const int n4 = ROWS * IIN / 4;
        for (int k = tid; k < n4; k += 256) dst[k] = src[k];
    }
    __syncthreads();

    // ---- per-row sums s1, s2 (wave-parallel, conflict-free lane-consecutive reads) ----
    constexpr int RPW = ROWS / 4;   // rows per wave (4 waves/block)
    #pragma unroll
    for (int r = 0; r < RPW; ++r) {
        const int b = wave * RPW + r;
        float p1 = 0.f, p2 = 0.f;
        for (int i = lane; i < IIN; i += 64) {
            float v = vis[b * IIN + i];
            p1 += v;
            p2 += v * v;
        }
        #pragma unroll
        for (int s = 32; s > 0; s >>= 1) {
            p1 += __shfl_xor(p1, s);
            p2 += __shfl_xor(p2, s);
        }
        if (lane == 0) { s1s[b] = p1; s2s[b] = p2; }
    }
    __syncthreads();

    // ---- collapsed conv constants (redundant per thread; tiny, L2-hot) ----
    float A0 = 0.f, A1 = 0.f, A2 = 0.f, Dd = c2b[0];
    #pragma unroll
    for (int h = 0; h < 8; ++h) {
        const float w2 = c2w[h];
        A0 += w2 * c1w[h * 3 + 0];
        A1 += w2 * c1w[h * 3 + 1];
        A2 += w2 * c1w[h * 3 + 2];
        Dd += w2 * c1b[h];
    }
    // batch_num robustness: expect int32; if bits look like a float, reinterpret.
    const int raw = bn[0];
    const float bnf = (raw > 0 && raw < 1000000) ? (float)raw : __int_as_float(raw);
    const float scale = 0.1f / bnf;

    // ---- one output column per wave: Wv[b][o] = dot(vi[b,:], W[o,:]) ----
    const int o = blockIdx.x * 4 + wave;
    float acc[ROWS];
    #pragma unroll
    for (int b = 0; b < ROWS; ++b) acc[b] = 0.f;

    const float4* Wrow = reinterpret_cast<const float4*>(W + o * IIN);
    for (int i4 = lane; i4 < IIN / 4; i4 += 64) {
        const float4 w4 = Wrow[i4];            // coalesced 1KB/wave
        #pragma unroll
        for (int b = 0; b < ROWS; ++b) {
            const float4 v4 = *reinterpret_cast<const float4*>(&vis[b * IIN + i4 * 4]);
            acc[b] += w4.x * v4.x + w4.y * v4.y + w4.z * v4.z + w4.w * v4.w;
        }
    }

    // ---- butterfly reduce each accumulator across 64 lanes ----
    #pragma unroll
    for (int b = 0; b < ROWS; ++b) {
        float v = acc[b];
        #pragma unroll
        for (int s = 32; s > 0; s >>= 1) v += __shfl_xor(v, s);
        acc[b] = v;
    }

    // ---- epilogue (lane 0 of each wave writes its column) ----
    if (lane == 0) {
        const float bo = bias[o];
        #pragma unroll
        for (int b = 0; b < ROWS; ++b) {
            const float Wv = acc[b];
            const float vj = fmaxf(Wv + bo, 0.f);
            const float delta = scale * (A0 * s2s[b] + A1 * Wv + (A2 * vj + Dd) * s1s[b]);
            outp[(brow0 + b) * Oout + o] = vj + delta;
        }
    }
}

extern "C" void kernel_launch(void* const* d_in, const int* in_sizes, int n_in,
                              void* d_out, int out_size, void* d_ws, size_t ws_size,
                              hipStream_t stream) {
    const float* x     = (const float*)d_in[0];
    const float* fc1_w = (const float*)d_in[1];
    const float* fc1_b = (const float*)d_in[2];
    const float* fc2_w = (const float*)d_in[3];
    const float* fc2_b = (const float*)d_in[4];
    const float* fc3_w = (const float*)d_in[5];
    const float* fc3_b = (const float*)d_in[6];
    const float* c1w   = (const float*)d_in[7];
    const float* c1b   = (const float*)d_in[8];
    const float* c2w   = (const float*)d_in[9];
    const float* c2b   = (const float*)d_in[10];
    const int*   bn    = (const int*)d_in[11];

    float* t1  = (float*)d_ws;          // [32, 512]
    float* t2  = t1 + 32 * 512;         // [32, 512]
    float* out = (float*)d_out;         // [32, 256]

    dim3 blk(256);
    // layer 1: I=1024 -> 512
    diffnet_layer<1024, 16><<<dim3(512 / 4, 2), blk, 0, stream>>>(
        x, fc1_w, fc1_b, c1w, c1b, c2w, c2b, bn, t1, 512);
    // layer 2: 512 -> 512
    diffnet_layer<512, 16><<<dim3(512 / 4, 2), blk, 0, stream>>>(
        t1, fc2_w, fc2_b, c1w, c1b, c2w, c2b, bn, t2, 512);
    // layer 3: 512 -> 256
    diffnet_layer<512, 16><<<dim3(256 / 4, 2), blk, 0, stream>>>(
        t2, fc3_w, fc3_b, c1w, c1b, c2w, c2b, bn, out, 256);
}